// Round 1
// baseline (979.872 us; speedup 1.0000x reference)
//
#include <hip/hip_runtime.h>
#include <hip/hip_bf16.h>

#define Bq 8
#define Cc 128
#define C4 512
#define Hh 256
#define Wf 256
#define H2 128
#define W2 128
#define HW2 16384

__device__ __forceinline__ float gelu_f(float x) {
    return 0.5f * x * (1.0f + erff(x * 0.70710678118654752f));
}

// ---------------- DWT: x (B,128,256,256) -> h1 (B,512,128,128) ----------------
__global__ __launch_bounds__(256) void k_dwt(const float* __restrict__ x,
                                             float* __restrict__ h1) {
    int tid = blockIdx.x * 256 + threadIdx.x;
    int j2 = tid & 63;            // 2 output pixels per thread
    int i  = (tid >> 6) & 127;
    int c  = (tid >> 13) & 127;
    int b  = tid >> 20;
    const float* xp = x + (((size_t)(b * Cc + c)) * Hh + 2 * i) * Wf + 4 * j2;
    float4 r0 = *(const float4*)xp;
    float4 r1 = *(const float4*)(xp + Wf);
    float ll0 = (r0.x + r0.y + r1.x + r1.y) * 0.5f;
    float lh0 = (r0.x + r0.y - r1.x - r1.y) * 0.5f;
    float hl0 = (r0.x - r0.y + r1.x - r1.y) * 0.5f;
    float hh0 = (r0.x - r0.y - r1.x + r1.y) * 0.5f;
    float ll1 = (r0.z + r0.w + r1.z + r1.w) * 0.5f;
    float lh1 = (r0.z + r0.w - r1.z - r1.w) * 0.5f;
    float hl1 = (r0.z - r0.w + r1.z - r1.w) * 0.5f;
    float hh1 = (r0.z - r0.w - r1.z + r1.w) * 0.5f;
    size_t qs = (size_t)Cc * HW2;
    size_t base = (((size_t)b * C4 + c) * H2 + i) * W2 + 2 * j2;
    *(float2*)(h1 + base)          = make_float2(ll0, ll1);
    *(float2*)(h1 + base + qs)     = make_float2(lh0, lh1);
    *(float2*)(h1 + base + 2 * qs) = make_float2(hl0, hl1);
    *(float2*)(h1 + base + 3 * qs) = make_float2(hh0, hh1);
}

// ---------------- f32 GEMM: C[b] = A(MxK) * B[b](KxN), epilogues ----------------
// EPI: 0 = plain store, 1 = +bias then gelu, 2 = +bias +res
template <int EPI>
__global__ __launch_bounds__(256) void k_gemm(const float* __restrict__ A,
                                              const float* __restrict__ B,
                                              float* __restrict__ C,
                                              const float* __restrict__ bias,
                                              const float* __restrict__ res,
                                              int M, int N, int K) {
    const int b = blockIdx.z;
    const float* Bp = B + (size_t)b * K * N;
    float* Cp = C + (size_t)b * M * N;
    const int m0 = blockIdx.y * 64, n0 = blockIdx.x * 64;
    __shared__ float As[16][68];
    __shared__ float Bs[16][64];
    const int t = threadIdx.x;
    const int ar = t >> 2, ak = (t & 3) * 4;
    const int bk = t >> 4, bn = (t & 15) * 4;
    const int tm = (t & 15) * 4, tn = (t >> 4) * 4;
    float acc[4][4] = {};
    const float* Aptr = A + (size_t)(m0 + ar) * K + ak;
    const float* Bptr = Bp + (size_t)bk * N + n0 + bn;
    for (int k0 = 0; k0 < K; k0 += 16) {
        float4 av = *(const float4*)(Aptr + k0);
        float4 bv = *(const float4*)(Bptr + (size_t)k0 * N);
        __syncthreads();
        As[ak + 0][ar] = av.x;
        As[ak + 1][ar] = av.y;
        As[ak + 2][ar] = av.z;
        As[ak + 3][ar] = av.w;
        *(float4*)&Bs[bk][bn] = bv;
        __syncthreads();
#pragma unroll
        for (int kk = 0; kk < 16; ++kk) {
            float4 a = *(const float4*)&As[kk][tm];
            float4 bb = *(const float4*)&Bs[kk][tn];
            float a4[4] = {a.x, a.y, a.z, a.w};
            float b4[4] = {bb.x, bb.y, bb.z, bb.w};
#pragma unroll
            for (int u = 0; u < 4; ++u)
#pragma unroll
                for (int v = 0; v < 4; ++v)
                    acc[u][v] = fmaf(a4[u], b4[v], acc[u][v]);
        }
    }
#pragma unroll
    for (int u = 0; u < 4; ++u) {
        int m = m0 + tm + u;
        size_t off = (size_t)m * N + n0 + tn;
        float4 v = make_float4(acc[u][0], acc[u][1], acc[u][2], acc[u][3]);
        if (EPI == 1) {
            float bi = bias[m];
            v.x = gelu_f(v.x + bi);
            v.y = gelu_f(v.y + bi);
            v.z = gelu_f(v.z + bi);
            v.w = gelu_f(v.w + bi);
        } else if (EPI == 2) {
            float bi = bias[m];
            float4 r = *(const float4*)(res + (size_t)b * M * N + off);
            v.x += bi + r.x;
            v.y += bi + r.y;
            v.z += bi + r.z;
            v.w += bi + r.w;
        }
        *(float4*)(Cp + off) = v;
    }
}

// ---------------- per-channel stats: sum & sumsq over (B, HW2) ----------------
__global__ __launch_bounds__(256) void k_stats_ch(const float* __restrict__ src,
                                                  float* __restrict__ sum,
                                                  float* __restrict__ sumsq,
                                                  int nc) {
    int c = blockIdx.x, b = blockIdx.y;
    const float* p = src + ((size_t)b * nc + c) * HW2;
    float s = 0.f, s2 = 0.f;
#pragma unroll
    for (int it = 0; it < 16; ++it) {
        float4 v = *(const float4*)(p + threadIdx.x * 4 + it * 1024);
        s += v.x + v.y + v.z + v.w;
        s2 += v.x * v.x + v.y * v.y + v.z * v.z + v.w * v.w;
    }
    __shared__ float ls[4], ls2[4];
#pragma unroll
    for (int off = 32; off; off >>= 1) {
        s += __shfl_down(s, off);
        s2 += __shfl_down(s2, off);
    }
    int wid = threadIdx.x >> 6;
    if ((threadIdx.x & 63) == 0) { ls[wid] = s; ls2[wid] = s2; }
    __syncthreads();
    if (threadIdx.x == 0) {
        float S = ls[0] + ls[1] + ls[2] + ls[3];
        float S2 = ls2[0] + ls2[1] + ls2[2] + ls2[3];
        atomicAdd(sum + c, S);
        atomicAdd(sumsq + c, S2);
    }
}

// ---------------- per-batch stats (LayerNorm over C,H,W) ----------------
__global__ __launch_bounds__(256) void k_stats_b(const float* __restrict__ src,
                                                 float* __restrict__ sum,
                                                 float* __restrict__ sumsq) {
    int b = blockIdx.y, s = blockIdx.x;
    const float* p = src + (size_t)b * Cc * HW2 + (size_t)s * 8192;
    float S = 0.f, S2 = 0.f;
#pragma unroll
    for (int it = 0; it < 8; ++it) {
        float4 v = *(const float4*)(p + threadIdx.x * 4 + it * 1024);
        S += v.x + v.y + v.z + v.w;
        S2 += v.x * v.x + v.y * v.y + v.z * v.z + v.w * v.w;
    }
    __shared__ float ls[4], ls2[4];
#pragma unroll
    for (int off = 32; off; off >>= 1) {
        S += __shfl_down(S, off);
        S2 += __shfl_down(S2, off);
    }
    int wid = threadIdx.x >> 6;
    if ((threadIdx.x & 63) == 0) { ls[wid] = S; ls2[wid] = S2; }
    __syncthreads();
    if (threadIdx.x == 0) {
        atomicAdd(sum + b, ls[0] + ls[1] + ls[2] + ls[3]);
        atomicAdd(sumsq + b, ls2[0] + ls2[1] + ls2[2] + ls2[3]);
    }
}

// ---------------- BN (128 ch) + GELU, in place ----------------
__global__ __launch_bounds__(256) void k_bn_gelu(float* __restrict__ p,
                                                 const float* __restrict__ sum,
                                                 const float* __restrict__ sq,
                                                 const float* __restrict__ g,
                                                 const float* __restrict__ bb) {
    size_t i = ((size_t)blockIdx.x * 256 + threadIdx.x) * 4;
    int c = (int)((i >> 14) & 127);
    const float invN = 1.0f / 131072.0f;
    float mu = sum[c] * invN;
    float var = sq[c] * invN - mu * mu;
    float rs = rsqrtf(var + 1e-5f);
    float sc = rs * g[c], sh = bb[c] - mu * sc;
    float4 v = *(float4*)(p + i);
    v.x = gelu_f(v.x * sc + sh);
    v.y = gelu_f(v.y * sc + sh);
    v.z = gelu_f(v.z * sc + sh);
    v.w = gelu_f(v.w * sc + sh);
    *(float4*)(p + i) = v;
}

// ---------------- LayerNorm apply, in place ----------------
__global__ __launch_bounds__(256) void k_ln(float* __restrict__ p,
                                            const float* __restrict__ sum,
                                            const float* __restrict__ sq,
                                            const float* __restrict__ g,
                                            const float* __restrict__ bb) {
    size_t i = ((size_t)blockIdx.x * 256 + threadIdx.x) * 4;
    int b = (int)(i >> 21);
    int c = (int)((i >> 14) & 127);
    const float invN = 1.0f / 2097152.0f;
    float mu = sum[b] * invN;
    float var = sq[b] * invN - mu * mu;
    float rs = rsqrtf(var + 1e-5f);
    float gc = g[c], bc = bb[c];
    float4 v = *(float4*)(p + i);
    v.x = (v.x - mu) * rs * gc + bc;
    v.y = (v.y - mu) * rs * gc + bc;
    v.z = (v.z - mu) * rs * gc + bc;
    v.w = (v.w - mu) * rs * gc + bc;
    *(float4*)(p + i) = v;
}

// ---------------- depthwise 3x3, pad 1 ----------------
__global__ __launch_bounds__(256) void k_dwconv(const float* __restrict__ x,
                                                float* __restrict__ y,
                                                const float* __restrict__ w,
                                                const float* __restrict__ bias) {
    int tid = blockIdx.x * 256 + threadIdx.x;
    int j0 = (tid & 31) * 4;
    int i  = (tid >> 5) & 127;
    int c  = (tid >> 12) & 127;
    int b  = tid >> 19;
    const float* wp = w + c * 9;
    float wt[9];
#pragma unroll
    for (int k = 0; k < 9; ++k) wt[k] = wp[k];
    const float* xp = x + ((size_t)(b * Cc + c) * H2 + i) * W2 + j0;
    float cl[3][6];
#pragma unroll
    for (int r = 0; r < 3; ++r) {
        int row = i - 1 + r;
        if (row >= 0 && row < H2) {
            const float* rp = xp + (r - 1) * W2;
            float4 m = *(const float4*)rp;
            cl[r][0] = (j0 > 0) ? rp[-1] : 0.f;
            cl[r][1] = m.x; cl[r][2] = m.y; cl[r][3] = m.z; cl[r][4] = m.w;
            cl[r][5] = (j0 + 4 < W2) ? rp[4] : 0.f;
        } else {
#pragma unroll
            for (int q = 0; q < 6; ++q) cl[r][q] = 0.f;
        }
    }
    float bi = bias[c];
    float4 out;
    float* op = &out.x;
#pragma unroll
    for (int v = 0; v < 4; ++v) {
        float a = bi;
#pragma unroll
        for (int r = 0; r < 3; ++r) {
            a = fmaf(wt[r * 3 + 0], cl[r][v + 0], a);
            a = fmaf(wt[r * 3 + 1], cl[r][v + 1], a);
            a = fmaf(wt[r * 3 + 2], cl[r][v + 2], a);
        }
        op[v] = a;
    }
    *(float4*)(y + ((size_t)(b * Cc + c) * H2 + i) * W2 + j0) = out;
}

// ---------------- BN (512 ch) + GELU + IDWT -> out (B,128,256,256) ----------------
__global__ __launch_bounds__(256) void k_bn_gelu_idwt(const float* __restrict__ y2,
                                                      float* __restrict__ out,
                                                      const float* __restrict__ sum,
                                                      const float* __restrict__ sq,
                                                      const float* __restrict__ g,
                                                      const float* __restrict__ bb) {
    int tid = blockIdx.x * 256 + threadIdx.x;
    int j2 = tid & 63;
    int i  = (tid >> 6) & 127;
    int c  = (tid >> 13) & 127;
    int b  = tid >> 20;
    const float invN = 1.0f / 131072.0f;
    size_t qs = (size_t)Cc * HW2;
    size_t base = (((size_t)b * C4 + c) * H2 + i) * W2 + 2 * j2;
    float sb[4][2];
#pragma unroll
    for (int q = 0; q < 4; ++q) {
        int ch = q * 128 + c;
        float mu = sum[ch] * invN;
        float var = sq[ch] * invN - mu * mu;
        float rs = rsqrtf(var + 1e-5f);
        float sc = rs * g[ch], sh = bb[ch] - mu * sc;
        float2 v = *(const float2*)(y2 + base + (size_t)q * qs);
        sb[q][0] = gelu_f(v.x * sc + sh);
        sb[q][1] = gelu_f(v.y * sc + sh);
    }
    float4 top, bot;
    float* tp = &top.x;
    float* bp = &bot.x;
#pragma unroll
    for (int px = 0; px < 2; ++px) {
        float ll = sb[0][px], lh = sb[1][px], hl = sb[2][px], hh = sb[3][px];
        tp[px * 2 + 0] = (ll + lh + hl + hh) * 0.5f;
        tp[px * 2 + 1] = (ll + lh - hl - hh) * 0.5f;
        bp[px * 2 + 0] = (ll - lh + hl - hh) * 0.5f;
        bp[px * 2 + 1] = (ll - lh - hl + hh) * 0.5f;
    }
    float* optr = out + ((size_t)(b * Cc + c) * Hh + 2 * i) * Wf + 4 * j2;
    *(float4*)optr = top;
    *(float4*)(optr + Wf) = bot;
}

extern "C" void kernel_launch(void* const* d_in, const int* in_sizes, int n_in,
                              void* d_out, int out_size, void* d_ws, size_t ws_size,
                              hipStream_t stream) {
    const float* x     = (const float*)d_in[0];
    const float* w_c1  = (const float*)d_in[1];
    const float* bn1_g = (const float*)d_in[3];
    const float* bn1_b = (const float*)d_in[4];
    const float* dw_w  = (const float*)d_in[5];
    const float* dw_b  = (const float*)d_in[6];
    const float* gn_g  = (const float*)d_in[7];
    const float* gn_b  = (const float*)d_in[8];
    const float* pw1_w = (const float*)d_in[9];
    const float* pw1_b = (const float*)d_in[10];
    const float* pw2_w = (const float*)d_in[11];
    const float* pw2_b = (const float*)d_in[12];
    const float* w_c2  = (const float*)d_in[13];
    const float* bn2_g = (const float*)d_in[15];
    const float* bn2_b = (const float*)d_in[16];
    float* out = (float*)d_out;

    float* ws = (float*)d_ws;
    size_t n512 = (size_t)Bq * C4 * HW2;   // 67,108,864 floats
    size_t n128 = (size_t)Bq * Cc * HW2;   // 16,777,216 floats
    float* buf512 = ws;
    float* bufA = buf512 + n512;
    float* bufB = bufA + n128;
    float* bufC = bufB + n128;
    float* stats = bufC + n128;
    size_t need = (n512 + 3 * n128 + 4096) * sizeof(float);
    if (ws_size < need) return;  // insufficient workspace: bail cleanly

    float* bn1_sum = stats;         // 128
    float* bn1_sq  = stats + 128;   // 128
    float* ln_sum  = stats + 256;   // 8
    float* ln_sq   = stats + 264;   // 8
    float* bn2_sum = stats + 512;   // 512
    float* bn2_sq  = stats + 1024;  // 512

    hipMemsetAsync(stats, 0, 4096 * sizeof(float), stream);

    // 1. DWT: x -> h1 (= buf512)
    k_dwt<<<32768, 256, 0, stream>>>(x, buf512);

    // 2. conv1 (no bias: BN absorbs it): bufA = w_c1 @ h1
    k_gemm<0><<<dim3(256, 2, Bq), 256, 0, stream>>>(w_c1, buf512, bufA,
                                                    nullptr, nullptr, 128, HW2, 512);

    // 3. BN1 stats + apply + gelu (in place, bufA = h = res)
    k_stats_ch<<<dim3(128, Bq), 256, 0, stream>>>(bufA, bn1_sum, bn1_sq, 128);
    k_bn_gelu<<<16384, 256, 0, stream>>>(bufA, bn1_sum, bn1_sq, bn1_g, bn1_b);

    // 4. depthwise 3x3: bufA -> bufB
    k_dwconv<<<16384, 256, 0, stream>>>(bufA, bufB, dw_w, dw_b);

    // 5. LN stats + apply (in place on bufB)
    k_stats_b<<<dim3(256, Bq), 256, 0, stream>>>(bufB, ln_sum, ln_sq);
    k_ln<<<16384, 256, 0, stream>>>(bufB, ln_sum, ln_sq, gn_g, gn_b);

    // 6. pw1 + bias + gelu: bufC = gelu(pw1_w @ bufB + b)
    k_gemm<1><<<dim3(256, 2, Bq), 256, 0, stream>>>(pw1_w, bufB, bufC,
                                                    pw1_b, nullptr, 128, HW2, 128);

    // 7. pw2 + bias + res: bufB = pw2_w @ bufC + b + bufA
    k_gemm<2><<<dim3(256, 2, Bq), 256, 0, stream>>>(pw2_w, bufC, bufB,
                                                    pw2_b, bufA, 128, HW2, 128);

    // 8. conv2 (no bias: BN absorbs it): buf512 = w_c2 @ bufB
    k_gemm<0><<<dim3(256, 8, Bq), 256, 0, stream>>>(w_c2, bufB, buf512,
                                                    nullptr, nullptr, 512, HW2, 128);

    // 9. BN2 stats + BN + gelu + IDWT -> out
    k_stats_ch<<<dim3(512, Bq), 256, 0, stream>>>(buf512, bn2_sum, bn2_sq, 512);
    k_bn_gelu_idwt<<<32768, 256, 0, stream>>>(buf512, out, bn2_sum, bn2_sq,
                                              bn2_g, bn2_b);
}

// Round 2
// 766.652 us; speedup vs baseline: 1.2781x; 1.2781x over previous
//
#include <hip/hip_runtime.h>
#include <hip/hip_bf16.h>

typedef unsigned short u16;
typedef unsigned int u32;
typedef __attribute__((ext_vector_type(8))) short short8;
typedef __attribute__((ext_vector_type(4))) float f32x4;

#define Bq 8
#define Cc 128
#define C4 512
#define Hh 256
#define Wf 256
#define H2 128
#define W2 128
#define HW2 16384
#define NPX (Bq * HW2)

__device__ __forceinline__ float gelu_f(float x) {
    return 0.5f * x * (1.0f + erff(x * 0.70710678118654752f));
}
__device__ __forceinline__ float bf2f(u16 u) {
    union { float f; u32 i; } v; v.i = ((u32)u) << 16; return v.f;
}
__device__ __forceinline__ u16 f2bf(float f) {
    union { float f; u32 i; } v; v.f = f;
    u32 r = v.i + 0x7FFFu + ((v.i >> 16) & 1u);   // round-to-nearest-even
    return (u16)(r >> 16);
}

// ---------------- weights f32 -> bf16 ----------------
__global__ __launch_bounds__(256) void k_wconv(const float* __restrict__ w_c1,
                                               const float* __restrict__ pw1,
                                               const float* __restrict__ pw2,
                                               const float* __restrict__ w_c2,
                                               u16* __restrict__ wb) {
    int i = blockIdx.x * 256 + threadIdx.x;   // 0..163839
    float v;
    if (i < 65536) v = w_c1[i];
    else if (i < 81920) v = pw1[i - 65536];
    else if (i < 98304) v = pw2[i - 81920];
    else v = w_c2[i - 98304];
    wb[i] = f2bf(v);
}

// ---------------- DWT: x NCHW f32 -> h1 pixel-major bf16 [b][pix][512] --------
__global__ __launch_bounds__(256) void k_dwt(const float* __restrict__ x,
                                             u16* __restrict__ h1) {
    __shared__ float lin[2 * 4224];            // [h][c*33 + e], padded (bank-safe)
    __shared__ __align__(16) u16 obuf[16 * 512];
    const int t = threadIdx.x;
    const int b = blockIdx.z, oi = blockIdx.y, jt = blockIdx.x;
    // A: cooperative coalesced read of two input rows (32 cols) for all 128 ch
    {
        int c = t & 127, h = t >> 7;
        const float* xp = x + (((long)(b * Cc + c)) * Hh + (2 * oi + h)) * Wf + jt * 32;
        float* lp = lin + h * 4224 + c * 33;
#pragma unroll
        for (int q = 0; q < 8; ++q) {
            float4 v = *(const float4*)(xp + q * 4);
            lp[q * 4 + 0] = v.x; lp[q * 4 + 1] = v.y;
            lp[q * 4 + 2] = v.z; lp[q * 4 + 3] = v.w;
        }
    }
    __syncthreads();
    // B: compute 4 subbands into pixel-major LDS tile
    {
        int c = t & 127, pg = t >> 7;
        const float* l0 = lin + c * 33;
        const float* l1 = lin + 4224 + c * 33;
#pragma unroll
        for (int u = 0; u < 8; ++u) {
            int p = pg * 8 + u;
            float x00 = l0[2 * p], x01 = l0[2 * p + 1];
            float x10 = l1[2 * p], x11 = l1[2 * p + 1];
            obuf[p * 512 + 0 * 128 + c] = f2bf((x00 + x01 + x10 + x11) * 0.5f);
            obuf[p * 512 + 1 * 128 + c] = f2bf((x00 + x01 - x10 - x11) * 0.5f);
            obuf[p * 512 + 2 * 128 + c] = f2bf((x00 - x01 + x10 - x11) * 0.5f);
            obuf[p * 512 + 3 * 128 + c] = f2bf((x00 - x01 - x10 + x11) * 0.5f);
        }
    }
    __syncthreads();
    // C: coalesced pixel-major store
    {
        int p = t >> 4, seg = t & 15;
        long opix = (long)b * HW2 + (long)oi * W2 + jt * 16 + p;
        const uint4* src = (const uint4*)(obuf + p * 512 + seg * 32);
        uint4* dst = (uint4*)(h1 + opix * 512 + seg * 32);
        dst[0] = src[0]; dst[1] = src[1]; dst[2] = src[2]; dst[3] = src[3];
    }
}

// ---------------- bf16 MFMA NT-GEMM: C[M][N] = A[M][K] * B[N][K]^T -------------
// A rows = output rows, B rows = output cols; both k-contiguous.
// EPI: 0 = plain bf16 store, 1 = +bias(col) gelu, 2 = +bias(col) +res
template <int EPI>
__global__ __launch_bounds__(256) void k_mfma(const u16* __restrict__ A,
                                              const u16* __restrict__ Bw,
                                              u16* __restrict__ C,
                                              const float* __restrict__ bias,
                                              const u16* __restrict__ res,
                                              int N, int K,
                                              long aBs, long bBs, long cBs) {
    __shared__ __align__(16) u16 lA[8192];     // [128 rows][64 k], XOR-swizzled
    __shared__ __align__(16) u16 lB[8192];
    const int t = threadIdx.x;
    const int lane = t & 63, w = t >> 6, wr = w >> 1, wc = w & 1;
    const int b = blockIdx.z;
    const int m0 = blockIdx.y * 128, n0 = blockIdx.x * 128;
    const u16* Ab = A + (long)b * aBs + (long)m0 * K;
    const u16* Bb = Bw + (long)b * bBs + (long)n0 * K;

    uint4 ra[4], rb[4];
#define GLOAD(dst, base, k0)                                                     \
    {                                                                            \
        _Pragma("unroll")                                                        \
        for (int i = 0; i < 4; ++i) {                                            \
            int s = i * 256 + t;                                                 \
            dst[i] = *(const uint4*)(base + (long)(s >> 3) * K + (k0) + (s & 7) * 8); \
        }                                                                        \
    }
#define LWRITE(lds, src)                                                         \
    {                                                                            \
        _Pragma("unroll")                                                        \
        for (int i = 0; i < 4; ++i) {                                            \
            int s = i * 256 + t;                                                 \
            int row_ = s >> 3, ch_ = s & 7;                                      \
            *(uint4*)((char*)lds + row_ * 128 + 16 * (ch_ ^ (row_ & 7))) = src[i]; \
        }                                                                        \
    }

    f32x4 acc[4][4];
#pragma unroll
    for (int i = 0; i < 4; ++i)
#pragma unroll
        for (int j = 0; j < 4; ++j) acc[i][j] = (f32x4){0.f, 0.f, 0.f, 0.f};

    GLOAD(ra, Ab, 0)
    GLOAD(rb, Bb, 0)
    const int r15 = lane & 15, kq = lane >> 4;
    for (int k0 = 0; k0 < K; k0 += 64) {
        __syncthreads();
        LWRITE(lA, ra)
        LWRITE(lB, rb)
        __syncthreads();
        if (k0 + 64 < K) { GLOAD(ra, Ab, k0 + 64) GLOAD(rb, Bb, k0 + 64) }
#pragma unroll
        for (int ks = 0; ks < 2; ++ks) {
            short8 af[4], bfv[4];
            const int ch = ks * 4 + kq;
#pragma unroll
            for (int mi = 0; mi < 4; ++mi) {
                int row = wr * 64 + mi * 16 + r15;
                af[mi] = *(const short8*)((const char*)lA + row * 128 + 16 * (ch ^ (row & 7)));
            }
#pragma unroll
            for (int ni = 0; ni < 4; ++ni) {
                int row = wc * 64 + ni * 16 + r15;
                bfv[ni] = *(const short8*)((const char*)lB + row * 128 + 16 * (ch ^ (row & 7)));
            }
#pragma unroll
            for (int mi = 0; mi < 4; ++mi)
#pragma unroll
                for (int ni = 0; ni < 4; ++ni)
                    acc[mi][ni] = __builtin_amdgcn_mfma_f32_16x16x32_bf16(
                        af[mi], bfv[ni], acc[mi][ni], 0, 0, 0);
        }
    }
    u16* Cb = C + (long)b * cBs;
    const u16* Rb = res + (long)b * cBs;
#pragma unroll
    for (int ni = 0; ni < 4; ++ni) {
        int col = n0 + wc * 64 + ni * 16 + r15;
        float bi = (EPI >= 1) ? bias[col] : 0.f;
#pragma unroll
        for (int mi = 0; mi < 4; ++mi) {
#pragma unroll
            for (int r = 0; r < 4; ++r) {
                int row = m0 + wr * 64 + mi * 16 + kq * 4 + r;
                float v = acc[mi][ni][r];
                if (EPI == 1) v = gelu_f(v + bi);
                if (EPI == 2) v = v + bi + bf2f(Rb[(long)row * N + col]);
                Cb[(long)row * N + col] = f2bf(v);
            }
        }
    }
#undef GLOAD
#undef LWRITE
}

// ---------------- per-channel stats over pixel-major [NPX][128] ----------------
__global__ __launch_bounds__(256) void k_stats_pm(const u16* __restrict__ src,
                                                  float* __restrict__ sum,
                                                  float* __restrict__ sq) {
    const int t = threadIdx.x;
    const int cg = t & 15, pr = t >> 4;
    long pbase = (long)blockIdx.x * 512;
    float s[8] = {}, s2[8] = {};
    for (int it = 0; it < 32; ++it) {
        long px = pbase + it * 16 + pr;
        uint4 raw = *(const uint4*)(src + px * 128 + cg * 8);
        const u16* pv = (const u16*)&raw;
#pragma unroll
        for (int u = 0; u < 8; ++u) {
            float v = bf2f(pv[u]);
            s[u] += v; s2[u] += v * v;
        }
    }
#pragma unroll
    for (int u = 0; u < 8; ++u) {
        s[u] += __shfl_down(s[u], 32);  s[u] += __shfl_down(s[u], 16);
        s2[u] += __shfl_down(s2[u], 32); s2[u] += __shfl_down(s2[u], 16);
    }
    __shared__ float red[2][4][16][8];
    int wv = t >> 6, ln = t & 63;
    if (ln < 16) {
#pragma unroll
        for (int u = 0; u < 8; ++u) { red[0][wv][ln][u] = s[u]; red[1][wv][ln][u] = s2[u]; }
    }
    __syncthreads();
    if (t < 128) {
        int g = t >> 3, u = t & 7;
        float a = red[0][0][g][u] + red[0][1][g][u] + red[0][2][g][u] + red[0][3][g][u];
        float b2 = red[1][0][g][u] + red[1][1][g][u] + red[1][2][g][u] + red[1][3][g][u];
        atomicAdd(sum + g * 8 + u, a);
        atomicAdd(sq + g * 8 + u, b2);
    }
}

// ---------------- per-batch stats (LayerNorm), pixel-major ----------------
__global__ __launch_bounds__(256) void k_stats_batch(const u16* __restrict__ src,
                                                     float* __restrict__ sum,
                                                     float* __restrict__ sq) {
    int b = blockIdx.y;
    long base = ((long)b * HW2 + (long)blockIdx.x * 512) * 128;
    float s = 0.f, s2 = 0.f;
    for (int it = 0; it < 32; ++it) {
        uint4 raw = *(const uint4*)(src + base + it * 2048 + threadIdx.x * 8);
        const u16* pv = (const u16*)&raw;
#pragma unroll
        for (int u = 0; u < 8; ++u) { float v = bf2f(pv[u]); s += v; s2 += v * v; }
    }
#pragma unroll
    for (int off = 32; off; off >>= 1) { s += __shfl_down(s, off); s2 += __shfl_down(s2, off); }
    __shared__ float r1[4], r2[4];
    if ((threadIdx.x & 63) == 0) { r1[threadIdx.x >> 6] = s; r2[threadIdx.x >> 6] = s2; }
    __syncthreads();
    if (threadIdx.x == 0) {
        atomicAdd(sum + b, r1[0] + r1[1] + r1[2] + r1[3]);
        atomicAdd(sq + b, r2[0] + r2[1] + r2[2] + r2[3]);
    }
}

// ---------------- per-channel stats over channel-major [C4][HW2] ----------------
__global__ __launch_bounds__(256) void k_stats_cm(const u16* __restrict__ src,
                                                  float* __restrict__ sum,
                                                  float* __restrict__ sq) {
    int c = blockIdx.x, b = blockIdx.y;
    long base = ((long)b * C4 + c) * HW2;
    float s = 0.f, s2 = 0.f;
    for (int it = 0; it < 8; ++it) {
        uint4 raw = *(const uint4*)(src + base + it * 2048 + threadIdx.x * 8);
        const u16* pv = (const u16*)&raw;
#pragma unroll
        for (int u = 0; u < 8; ++u) { float v = bf2f(pv[u]); s += v; s2 += v * v; }
    }
#pragma unroll
    for (int off = 32; off; off >>= 1) { s += __shfl_down(s, off); s2 += __shfl_down(s2, off); }
    __shared__ float r1[4], r2[4];
    if ((threadIdx.x & 63) == 0) { r1[threadIdx.x >> 6] = s; r2[threadIdx.x >> 6] = s2; }
    __syncthreads();
    if (threadIdx.x == 0) {
        atomicAdd(sum + c, r1[0] + r1[1] + r1[2] + r1[3]);
        atomicAdd(sq + c, r2[0] + r2[1] + r2[2] + r2[3]);
    }
}

// ---------------- BN1 apply + gelu: bufA -> bufH (bf16, pixel-major) ----------
__global__ __launch_bounds__(256) void k_bn1_gelu(const u16* __restrict__ in,
                                                  u16* __restrict__ out,
                                                  const float* __restrict__ sum,
                                                  const float* __restrict__ sq,
                                                  const float* __restrict__ g,
                                                  const float* __restrict__ bb) {
    long e = ((long)blockIdx.x * 256 + threadIdx.x) * 8;
    int c0 = (int)(e & 127);
    uint4 raw = *(const uint4*)(in + e);
    u16* pv = (u16*)&raw;
    const float invN = 1.0f / 131072.0f;
#pragma unroll
    for (int u = 0; u < 8; ++u) {
        int c = c0 + u;
        float mu = sum[c] * invN;
        float var = sq[c] * invN - mu * mu;
        float rs = rsqrtf(var + 1e-5f);
        float sc = rs * g[c], sh = bb[c] - mu * sc;
        pv[u] = f2bf(gelu_f(bf2f(pv[u]) * sc + sh));
    }
    *(uint4*)(out + e) = raw;
}

// ---------------- LayerNorm apply in place (pixel-major) ----------------
__global__ __launch_bounds__(256) void k_ln(u16* __restrict__ p,
                                            const float* __restrict__ sum,
                                            const float* __restrict__ sq,
                                            const float* __restrict__ g,
                                            const float* __restrict__ bb) {
    long e = ((long)blockIdx.x * 256 + threadIdx.x) * 8;
    int b = (int)(e >> 21);
    int c0 = (int)(e & 127);
    const float invN = 1.0f / 2097152.0f;
    float mu = sum[b] * invN;
    float var = sq[b] * invN - mu * mu;
    float rs = rsqrtf(var + 1e-5f);
    uint4 raw = *(const uint4*)(p + e);
    u16* pv = (u16*)&raw;
#pragma unroll
    for (int u = 0; u < 8; ++u) {
        int c = c0 + u;
        pv[u] = f2bf((bf2f(pv[u]) - mu) * rs * g[c] + bb[c]);
    }
    *(uint4*)(p + e) = raw;
}

// ---------------- depthwise 3x3 NHWC bf16 ----------------
__global__ __launch_bounds__(256) void k_dwconv(const u16* __restrict__ x,
                                                u16* __restrict__ y,
                                                const float* __restrict__ w,
                                                const float* __restrict__ bias) {
    __shared__ float wl[1152];
    const int t = threadIdx.x;
    if (t < 144) {
        *(float4*)(wl + t * 8)     = *(const float4*)(w + t * 8);
        *(float4*)(wl + t * 8 + 4) = *(const float4*)(w + t * 8 + 4);
    }
    __syncthreads();
    const int cg = t & 15, jj = t >> 4;
    const int j = blockIdx.x * 16 + jj, i = blockIdx.y, b = blockIdx.z;
    const u16* xb = x + (long)b * HW2 * 128;
    float acc[8];
#pragma unroll
    for (int u = 0; u < 8; ++u) acc[u] = bias[cg * 8 + u];
#pragma unroll
    for (int di = -1; di <= 1; ++di) {
        int row = i + di;
        if (row < 0 || row >= H2) continue;
#pragma unroll
        for (int dj = -1; dj <= 1; ++dj) {
            int col = j + dj;
            if (col < 0 || col >= W2) continue;
            uint4 raw = *(const uint4*)(xb + ((long)row * W2 + col) * 128 + cg * 8);
            const u16* pv = (const u16*)&raw;
            int tap = (di + 1) * 3 + (dj + 1);
#pragma unroll
            for (int u = 0; u < 8; ++u)
                acc[u] = fmaf(bf2f(pv[u]), wl[(cg * 8 + u) * 9 + tap], acc[u]);
        }
    }
    uint4 out; u16* ov = (u16*)&out;
#pragma unroll
    for (int u = 0; u < 8; ++u) ov[u] = f2bf(acc[u]);
    *(uint4*)(y + ((long)b * HW2 + (long)i * W2 + j) * 128 + cg * 8) = out;
}

// ---------------- BN2 + GELU + IDWT: z channel-major bf16 -> out f32 NCHW -----
__global__ __launch_bounds__(256) void k_bn2_gelu_idwt(const u16* __restrict__ z,
                                                       float* __restrict__ out,
                                                       const float* __restrict__ sum,
                                                       const float* __restrict__ sq,
                                                       const float* __restrict__ g,
                                                       const float* __restrict__ bb) {
    int tid = blockIdx.x * 256 + threadIdx.x;
    int j2 = tid & 63;
    int i  = (tid >> 6) & 127;
    int c  = (tid >> 13) & 127;
    int b  = tid >> 20;
    const float invN = 1.0f / 131072.0f;
    long qs = (long)Cc * HW2;
    long base = (((long)b * C4 + c) * H2 + i) * W2 + 2 * j2;
    float sb[4][2];
#pragma unroll
    for (int q = 0; q < 4; ++q) {
        int ch = q * 128 + c;
        float mu = sum[ch] * invN;
        float var = sq[ch] * invN - mu * mu;
        float rs = rsqrtf(var + 1e-5f);
        float sc = rs * g[ch], sh = bb[ch] - mu * sc;
        u32 raw = *(const u32*)(z + base + (long)q * qs);
        sb[q][0] = gelu_f(bf2f((u16)(raw & 0xFFFFu)) * sc + sh);
        sb[q][1] = gelu_f(bf2f((u16)(raw >> 16)) * sc + sh);
    }
    float4 top, bot;
    float* tp = &top.x;
    float* bp = &bot.x;
#pragma unroll
    for (int px = 0; px < 2; ++px) {
        float ll = sb[0][px], lh = sb[1][px], hl = sb[2][px], hh = sb[3][px];
        tp[px * 2 + 0] = (ll + lh + hl + hh) * 0.5f;
        tp[px * 2 + 1] = (ll + lh - hl - hh) * 0.5f;
        bp[px * 2 + 0] = (ll - lh + hl - hh) * 0.5f;
        bp[px * 2 + 1] = (ll - lh - hl + hh) * 0.5f;
    }
    float* optr = out + ((long)(b * Cc + c) * Hh + 2 * i) * Wf + 4 * j2;
    *(float4*)optr = top;
    *(float4*)(optr + Wf) = bot;
}

extern "C" void kernel_launch(void* const* d_in, const int* in_sizes, int n_in,
                              void* d_out, int out_size, void* d_ws, size_t ws_size,
                              hipStream_t stream) {
    const float* x     = (const float*)d_in[0];
    const float* w_c1  = (const float*)d_in[1];
    const float* bn1_g = (const float*)d_in[3];
    const float* bn1_b = (const float*)d_in[4];
    const float* dw_w  = (const float*)d_in[5];
    const float* dw_b  = (const float*)d_in[6];
    const float* gn_g  = (const float*)d_in[7];
    const float* gn_b  = (const float*)d_in[8];
    const float* pw1_w = (const float*)d_in[9];
    const float* pw1_b = (const float*)d_in[10];
    const float* pw2_w = (const float*)d_in[11];
    const float* pw2_b = (const float*)d_in[12];
    const float* w_c2  = (const float*)d_in[13];
    const float* bn2_g = (const float*)d_in[15];
    const float* bn2_b = (const float*)d_in[16];
    float* out = (float*)d_out;

    const size_t n512 = (size_t)Bq * C4 * HW2;   // 67,108,864
    const size_t n128 = (size_t)Bq * Cc * HW2;   // 16,777,216
    u16* h1   = (u16*)d_ws;        // DWT out, pixel-major [b][pix][512]
    u16* z2   = h1;                // conv2 out reuses h1 (disjoint lifetime)
    u16* bufA = h1 + n512;         // conv1 raw out [b][pix][128]
    u16* bufH = bufA + n128;       // post BN1+gelu (= residual)
    u16* bufD = bufH + n128;       // dwconv out, then LN in place
    u16* bufP = bufD + n128;       // pw1 out
    u16* bufY = bufP + n128;       // pw2 out
    u16* wb   = bufY + n128;       // bf16 weights: w_c1|pw1|pw2|w_c2
    float* stats = (float*)(wb + 163840);
    size_t need = (n512 + 5 * n128 + 163840) * 2 + 4096 * 4;
    if (ws_size < need) return;

    float* bn1_sum = stats;
    float* bn1_sq  = stats + 128;
    float* ln_sum  = stats + 256;
    float* ln_sq   = stats + 264;
    float* bn2_sum = stats + 512;
    float* bn2_sq  = stats + 1024;

    hipMemsetAsync(stats, 0, 4096 * sizeof(float), stream);

    // 0. weights -> bf16
    k_wconv<<<640, 256, 0, stream>>>(w_c1, pw1_w, pw2_w, w_c2, wb);

    // 1. DWT -> h1 (pixel-major bf16)
    k_dwt<<<dim3(8, 128, 8), 256, 0, stream>>>(x, h1);

    // 2. conv1: bufA[pix][128] = h1[pix][512] x w_c1[128][512]^T
    k_mfma<0><<<dim3(1, 128, 8), 256, 0, stream>>>(
        h1, wb, bufA, nullptr, bufA, 128, 512,
        (long)HW2 * 512, 0, (long)HW2 * 128);

    // 3. BN1 stats + apply + gelu -> bufH
    k_stats_pm<<<256, 256, 0, stream>>>(bufA, bn1_sum, bn1_sq);
    k_bn1_gelu<<<8192, 256, 0, stream>>>(bufA, bufH, bn1_sum, bn1_sq, bn1_g, bn1_b);

    // 4. depthwise 3x3 (NHWC): bufH -> bufD
    k_dwconv<<<dim3(8, 128, 8), 256, 0, stream>>>(bufH, bufD, dw_w, dw_b);

    // 5. LN stats + apply in place
    k_stats_batch<<<dim3(32, 8), 256, 0, stream>>>(bufD, ln_sum, ln_sq);
    k_ln<<<8192, 256, 0, stream>>>(bufD, ln_sum, ln_sq, gn_g, gn_b);

    // 6. pw1 + bias + gelu: bufP = bufD x pw1_w^T
    k_mfma<1><<<dim3(1, 128, 8), 256, 0, stream>>>(
        bufD, wb + 65536, bufP, pw1_b, bufP, 128, 128,
        (long)HW2 * 128, 0, (long)HW2 * 128);

    // 7. pw2 + bias + residual: bufY = bufP x pw2_w^T + bufH
    k_mfma<2><<<dim3(1, 128, 8), 256, 0, stream>>>(
        bufP, wb + 81920, bufY, pw2_b, bufH, 128, 128,
        (long)HW2 * 128, 0, (long)HW2 * 128);

    // 8. conv2 (channel-major out): z2[ch][pix] = w_c2[512][128] x bufY[pix][128]^T
    k_mfma<0><<<dim3(128, 4, 8), 256, 0, stream>>>(
        wb + 98304, bufY, z2, nullptr, z2, 16384, 128,
        0, (long)HW2 * 128, (long)C4 * HW2);

    // 9. BN2 stats + BN + gelu + IDWT -> out
    k_stats_cm<<<dim3(512, 8), 256, 0, stream>>>(z2, bn2_sum, bn2_sq);
    k_bn2_gelu_idwt<<<32768, 256, 0, stream>>>(z2, out, bn2_sum, bn2_sq, bn2_g, bn2_b);
}